// Round 4
// baseline (332.551 us; speedup 1.0000x reference)
//
#include <hip/hip_runtime.h>

#define NN 100000
#define NE 600000
#define ET (NE + NN)
#define D 128
#define NREL 16
#define NSLICE 8
#define SLICE_N 12500            // NN / NSLICE exact
#define BPS 17                   // bins per slice: 16 rel + 1 self
#define NBIN (NSLICE * BPS)      // 136
#define SCANB 391                // 391*256 = 100096 >= NN
#define TPB 4                    // tiles per gemm block
// worst-case tiles in ONE slice: all NE edges there (+16 bin pads) + its self rows
#define MAXSLICET (NE / 64 + 16 + SLICE_N / 64 + 1)
#define GEMMG (NSLICE * ((MAXSLICET + TPB - 1) / TPB))
#define WGRID 1088  // 17*16384/256

typedef short short8 __attribute__((ext_vector_type(8)));
typedef float f32x4 __attribute__((ext_vector_type(4)));
typedef unsigned int u32x4 __attribute__((ext_vector_type(4)));

// meta layout (ints); bins are slice-major: bin = slice*BPS + rel (rel 16 = self)
#define C0 0                     // counts[NBIN]
#define O0 136                   // offsets[NBIN+1]
#define CU0 273                  // cursors[NBIN]
#define T0 409                   // tileoff[NBIN+1]   (total 546 ints)

// ws layout (bytes)
#define WT_OFF   0                 // 17*128*128 bf16 = 557056
#define META_OFF 557056            // 2560 (546 ints used)
#define DH_OFF   559616            // dstHist: 100000 ints
#define DO_OFF   959616            // dstOff: 100001 ints (+pad)
#define DC_OFF   1359624           // dstCursor: 100000 ints
#define BS_OFF   1759624           // blockSums: 391 ints (+pad, keeps SCP 8-aligned)
#define SCP_OFF  1761632           // sCP: 700064 int2
#define SR_OFF   7362144           // sRow (fallback only): 700000 ints
#define XB_OFF   10162144          // xb: 100000*128 bf16
#define MSGB_OFF 35762144          // msg (mode B)
#define MSGA_OFF 10162144          // msg (mode A, no xb)
#define NEED_B   (MSGB_OFF + (size_t)ET * 128 * 2)
#define NEED_A   (MSGA_OFF + (size_t)ET * 128 * 2)

__device__ __forceinline__ unsigned short f2bf(float f) {
  unsigned u = __builtin_bit_cast(unsigned, f);
  u += 0x7fffu + ((u >> 16) & 1u);   // RNE; inputs finite/normal
  return (unsigned short)(u >> 16);
}

// LDS-only barrier: no vmcnt drain (prefetch regs / nt stores stay in flight).
__device__ __forceinline__ void lds_barrier() {
  asm volatile("s_waitcnt lgkmcnt(0)" ::: "memory");
  __builtin_amdgcn_s_barrier();
}

// blockIdx < WGRID: wT[r][o][i] = sum_b coef[r,b]*bases[b][i][o]; slot16 = w_self.
// else: x fp32 -> xb bf16 (4 elems/thread).
__global__ __launch_bounds__(256) void k_prep(const float* __restrict__ bases,
    const float* __restrict__ coef, const float* __restrict__ w_self,
    unsigned short* __restrict__ wT, const float* __restrict__ x,
    unsigned short* __restrict__ xb)
{
  if (blockIdx.x < WGRID) {
    int idx = blockIdx.x * 256 + threadIdx.x;   // < 17*16384
    int r = idx >> 14;
    int t = idx & 16383;
    float v;
    if (r < 16) {
      int o = t >> 7, i = t & 127;
      float acc = 0.f;
      #pragma unroll
      for (int b = 0; b < 8; ++b)
        acc += coef[r * 8 + b] * bases[b * 16384 + i * 128 + o];
      v = acc;
    } else {
      v = w_self[t];
    }
    wT[idx] = f2bf(v);
  } else {
    int i = (blockIdx.x - WGRID) * 256 + threadIdx.x;
    if (i >= NN * D / 4) return;
    f32x4 f = __builtin_nontemporal_load((const f32x4*)(x + (size_t)i * 4));
    unsigned short s0 = f2bf(f[0]), s1 = f2bf(f[1]), s2 = f2bf(f[2]), s3 = f2bf(f[3]);
    unsigned long long pk = (unsigned long long)s0 | ((unsigned long long)s1 << 16)
                          | ((unsigned long long)s2 << 32) | ((unsigned long long)s3 << 48);
    *(unsigned long long*)(xb + (size_t)i * 4) = pk;   // cached: xb is the reuse set
  }
}

// (slice,rel) histogram (LDS) + dst histogram (global atomics)
__global__ __launch_bounds__(256) void k_hist(const int* __restrict__ ei,
    const int* __restrict__ et, int* __restrict__ meta, int* __restrict__ dstHist)
{
  __shared__ int h[NBIN];
  int tid = threadIdx.x;
  if (tid < NBIN) h[tid] = 0;
  __syncthreads();
  for (int e = blockIdx.x * 256 + tid; e < NE; e += gridDim.x * 256) {
    int src = ei[NE + e];
    atomicAdd(&h[(src / SLICE_N) * BPS + et[e]], 1);
    atomicAdd(&dstHist[ei[e]], 1);
  }
  __syncthreads();
  if (tid < NBIN) atomicAdd(&meta[C0 + tid], h[tid]);
}

__global__ __launch_bounds__(256) void k_scan1(const int* __restrict__ dstHist,
    int* __restrict__ dstOff, int* __restrict__ blockSums)
{
  __shared__ int sh[256];
  int tid = threadIdx.x;
  int d = blockIdx.x * 256 + tid;
  int v = (d < NN) ? (dstHist[d] + 1) : 0;   // +1: virtual self edge
  sh[tid] = v;
  __syncthreads();
  #pragma unroll
  for (int ofs = 1; ofs < 256; ofs <<= 1) {
    int t = (tid >= ofs) ? sh[tid - ofs] : 0;
    __syncthreads();
    sh[tid] += t;
    __syncthreads();
  }
  if (d < NN) dstOff[d] = sh[tid] - v;
  if (tid == 255) blockSums[blockIdx.x] = sh[tid];
}

__global__ __launch_bounds__(512) void k_scan2(int* __restrict__ blockSums, int* __restrict__ meta)
{
  __shared__ int sh[SCANB];
  int tid = threadIdx.x;
  if (tid < SCANB) sh[tid] = blockSums[tid];
  __syncthreads();
  if (tid == 0) {
    int run = 0;
    for (int i = 0; i < SCANB; ++i) { int c = sh[i]; sh[i] = run; run += c; }
    #pragma unroll
    for (int s = 0; s < NSLICE; ++s) meta[C0 + s * BPS + 16] = SLICE_N;
    int off = 0, toff = 0;
    for (int bn = 0; bn < NBIN; ++bn) {
      meta[O0 + bn] = off;
      meta[CU0 + bn] = off;
      meta[T0 + bn] = toff;
      int c = meta[C0 + bn];
      off += c;
      toff += (c + 63) >> 6;
    }
    meta[O0 + NBIN] = off;
    meta[T0 + NBIN] = toff;
  }
  __syncthreads();
  if (tid < SCANB) blockSums[tid] = sh[tid];
}

__global__ __launch_bounds__(256) void k_scan3(int* __restrict__ dstOff,
    const int* __restrict__ blockSums, int* __restrict__ dstCursor,
    int2* __restrict__ sCP, const int* __restrict__ meta)
{
  int tid = threadIdx.x;
  int d = blockIdx.x * 256 + tid;
  int base = blockSums[blockIdx.x];
  if (d < NN) {
    int o = dstOff[d] + base;
    dstOff[d] = o;
    dstCursor[d] = o + 1;
    int s = d / SLICE_N;
    int pos = meta[O0 + s * BPS + 16] + (d - s * SLICE_N);
    sCP[pos] = make_int2(d, o);
  }
  if (d == NN) dstOff[NN] = ET;
}

__global__ __launch_bounds__(256) void k_self0(int2* __restrict__ sCP, int* __restrict__ sRow,
    const int* __restrict__ meta)
{
  int n = blockIdx.x * 256 + threadIdx.x;
  if (n < NN) {
    int s = n / SLICE_N;
    int pos = meta[O0 + s * BPS + 16] + (n - s * SLICE_N);
    sCP[pos] = make_int2(n, 0);
    sRow[pos] = n;
  }
}

__global__ __launch_bounds__(256) void k_scatter(const int* __restrict__ ei, const int* __restrict__ et,
    int* __restrict__ meta, int2* __restrict__ sCP, int* __restrict__ sRow,
    int* __restrict__ dstCursor, int doMsg)
{
  __shared__ int h[NBIN], base[NBIN], lh[NBIN];
  int tid = threadIdx.x;
  int start = blockIdx.x * 4096;
  int end = min(NE, start + 4096);
  if (tid < NBIN) { h[tid] = 0; lh[tid] = 0; }
  __syncthreads();
  for (int e = start + tid; e < end; e += 256) {
    int src = ei[NE + e];
    atomicAdd(&h[(src / SLICE_N) * BPS + et[e]], 1);
  }
  __syncthreads();
  if (tid < NBIN) base[tid] = atomicAdd(&meta[CU0 + tid], h[tid]);
  __syncthreads();
  for (int e = start + tid; e < end; e += 256) {
    int src = ei[NE + e];
    int bin = (src / SLICE_N) * BPS + et[e];
    int row = ei[e];
    int pos = base[bin] + atomicAdd(&lh[bin], 1);
    int slot = doMsg ? atomicAdd(&dstCursor[row], 1) : 0;
    sCP[pos] = make_int2(src, slot);
    if (!doMsg) sRow[pos] = row;
  }
}

// slice = blockIdx%8 (round-robin block->XCD): all gathers of this block hit one
// 3.2MB xb slice -> L2-resident per XCD. Fast path: LDS-only barriers + reg
// prefetch pipeline (R3-validated). Fallback: full __syncthreads.
__global__ __launch_bounds__(256) void k_gemm(const float* __restrict__ xf,
    const unsigned short* __restrict__ xb,
    const unsigned short* __restrict__ wT, const int* __restrict__ meta,
    const int2* __restrict__ sCP, const int* __restrict__ sRow,
    unsigned short* __restrict__ msg, float* __restrict__ out,
    int xbf, int msgmode)
{
  __shared__ short As[64 * 17 * 8];
  __shared__ short Es[64 * 136];
  __shared__ int Pos2[2][64];
  __shared__ int Rows[64];
  __shared__ int Cw[BPS], Ow[BPS], Tw[BPS + 1];

  int tid = threadIdx.x;
  int sl = blockIdx.x & 7;
  int chunk = blockIdx.x >> 3;
  if (tid < BPS) Cw[tid] = meta[C0 + sl * BPS + tid];
  if (tid >= 32 && tid < 32 + BPS) Ow[tid - 32] = meta[O0 + sl * BPS + (tid - 32)];
  if (tid >= 64 && tid < 64 + BPS + 1) Tw[tid - 64] = meta[T0 + sl * BPS + (tid - 64)];
  __syncthreads();
  int tile0 = Tw[0];
  int sliceNT = Tw[BPS] - tile0;
  int lt0 = chunk * TPB;
  if (lt0 >= sliceNT) return;

  int lane = tid & 63, wave = tid >> 6;
  int q = lane >> 4, l15 = lane & 15;
  int m = tid >> 2, ug = tid & 3;

  if (xbf && msgmode) {
    int j = 0;   // rolling bin cursor within slice (monotone over tiles)
    short8 pfS[4]; int cyS; bool vS; int rS, nrS;
    int2 cpG; bool vG; int rG, nrG;
    int2 cpP; bool vP; int rP, nrP;

    // ---- prologue: S = tile lt0 ----
    {
      int b = tile0 + lt0;
      while (j < 16 && Tw[j + 1] <= b) ++j;
      int e0 = Ow[j] + (b - Tw[j]) * 64;
      nrS = min(64, Ow[j] + Cw[j] - e0);
      rS = j;
      vS = m < nrS;
      int2 cp = sCP[vS ? (e0 + m) : e0];
      cyS = cp.y;
      const unsigned short* xr = xb + (size_t)cp.x * 128;
      #pragma unroll
      for (int s = 0; s < 4; ++s) {
        short8 v = (short8)(short)0;
        if (vS) v = *(const short8*)(xr + (ug * 4 + s) * 8);
        pfS[s] = v;
      }
    }
    // ---- prologue: G = tile lt0+1 (sCP only) ----
    if (TPB > 1 && lt0 + 1 < sliceNT) {
      int b = tile0 + lt0 + 1;
      while (j < 16 && Tw[j + 1] <= b) ++j;
      int e0 = Ow[j] + (b - Tw[j]) * 64;
      nrG = min(64, Ow[j] + Cw[j] - e0);
      rG = j;
      vG = m < nrG;
      cpG = sCP[vG ? (e0 + m) : e0];
    } else { vG = false; nrG = 0; rG = rS; cpG = make_int2(0, 0); }

    int rprev = -1;
    short8 bfr[2][4];
    for (int ti = 0; ti < TPB; ++ti) {
      int lt = lt0 + ti;
      if (lt >= sliceNT) break;
      int curR = rS, curNr = nrS;

      // ---- 1. stage S from regs ----
      #pragma unroll
      for (int s = 0; s < 4; ++s)
        *(short8*)&As[(m * 17 + ug * 4 + s) * 8] = pfS[s];
      if (ug == 0) Pos2[ti & 1][m] = vS ? cyS : 0;

      // ---- 2. issue sCP load for tile lt+2 ----
      if (ti + 2 < TPB && lt + 2 < sliceNT) {
        int bp = tile0 + lt + 2;
        while (j < 16 && Tw[j + 1] <= bp) ++j;
        int e0 = Ow[j] + (bp - Tw[j]) * 64;
        nrP = min(64, Ow[j] + Cw[j] - e0);
        rP = j;
        vP = m < nrP;
        cpP = sCP[vP ? (e0 + m) : e0];
      } else { vP = false; nrP = 0; rP = rG; cpP = make_int2(0, 0); }

      // ---- 3. issue gathers for G (in flight across barriers) ----
      short8 pfN[4];
      {
        const unsigned short* xr = xb + (size_t)cpG.x * 128;
        #pragma unroll
        for (int s = 0; s < 4; ++s) {
          short8 v = (short8)(short)0;
          if (vG) v = *(const short8*)(xr + (ug * 4 + s) * 8);
          pfN[s] = v;
        }
      }

      // ---- 4. B frags (reload only on rel change) ----
      if (curR != rprev) {
        const unsigned short* wr = wT + curR * 16384;
        #pragma unroll
        for (int ns = 0; ns < 2; ++ns)
          #pragma unroll
          for (int kk = 0; kk < 4; ++kk)
            bfr[ns][kk] = *(const short8*)(wr + (wave * 32 + ns * 16 + l15) * 128 + kk * 32 + q * 8);
        rprev = curR;
      }

      lds_barrier();   // bar1: As/Pos2 visible; prior Es reads drained

      // ---- 5. MFMA ----
      f32x4 acc[4][2];
      #pragma unroll
      for (int ms = 0; ms < 4; ++ms)
        #pragma unroll
        for (int ns = 0; ns < 2; ++ns)
          acc[ms][ns] = (f32x4){0.f, 0.f, 0.f, 0.f};
      #pragma unroll
      for (int kk = 0; kk < 4; ++kk) {
        short8 af[4];
        #pragma unroll
        for (int ms = 0; ms < 4; ++ms)
          af[ms] = *(const short8*)&As[((ms * 16 + l15) * 17 + kk * 4 + q) * 8];
        #pragma unroll
        for (int ms = 0; ms < 4; ++ms)
          #pragma unroll
          for (int ns = 0; ns < 2; ++ns)
            acc[ms][ns] = __builtin_amdgcn_mfma_f32_16x16x32_bf16(af[ms], bfr[ns][kk], acc[ms][ns], 0, 0, 0);
      }

      // ---- 6. transpose to Es ----
      #pragma unroll
      for (int ms = 0; ms < 4; ++ms)
        #pragma unroll
        for (int ns = 0; ns < 2; ++ns)
          #pragma unroll
          for (int reg = 0; reg < 4; ++reg)
            Es[(ms * 16 + q * 4 + reg) * 136 + wave * 32 + ns * 16 + l15] =
                (short)f2bf(acc[ms][ns][reg]);

      lds_barrier();   // bar2: Es visible; MFMA As-reads drained

      // ---- 7. full-row msg stores (nontemporal) ----
      #pragma unroll
      for (int i = 0; i < 4; ++i) {
        int row = wave * 16 + i * 4 + q;
        short8 v = *(const short8*)&Es[row * 136 + l15 * 8];
        if (row < curNr)
          __builtin_nontemporal_store(v,
              (short8*)(msg + (size_t)Pos2[ti & 1][row] * 128 + l15 * 8));
      }

      // ---- 8. rotate pipeline ----
      #pragma unroll
      for (int s = 0; s < 4; ++s) pfS[s] = pfN[s];
      cyS = cpG.y; vS = vG; rS = rG; nrS = nrG;
      cpG = cpP;   vG = vP; rG = rP; nrG = nrP;
    }
    return;
  }

  // ---------------- generic fallback ----------------
  int rprev = -1;
  short8 bfr[2][4];
  for (int ti = 0; ti < TPB; ++ti) {
    int lt = lt0 + ti;
    if (lt >= sliceNT) break;
    int b = tile0 + lt;
    int j = 0;
    while (j < 16 && Tw[j + 1] <= b) ++j;
    int e0 = Ow[j] + (b - Tw[j]) * 64;
    int nrows = min(64, Ow[j] + Cw[j] - e0);

    bool valid = m < nrows;
    int e = valid ? (e0 + m) : e0;
    int2 cp = sCP[e];
    if (ug == 0) {
      Pos2[0][m] = valid ? cp.y : 0;
      if (!msgmode) Rows[m] = valid ? sRow[e] : 0;
    }
    int c = cp.x;
    if (xbf) {
      const unsigned short* xr = xb + (size_t)c * 128;
      #pragma unroll
      for (int s = 0; s < 4; ++s) {
        int u = ug * 4 + s;
        short8 pk = (short8)(short)0;
        if (valid) pk = *(const short8*)(xr + u * 8);
        *(short8*)&As[(m * 17 + u) * 8] = pk;
      }
    } else {
      const float* xr = xf + (size_t)c * 128;
      #pragma unroll
      for (int s = 0; s < 4; ++s) {
        int u = ug * 4 + s;
        float4 f0 = make_float4(0.f, 0.f, 0.f, 0.f), f1 = f0;
        if (valid) {
          f0 = *(const float4*)(xr + u * 8);
          f1 = *(const float4*)(xr + u * 8 + 4);
        }
        short8 pk;
        pk[0] = (short)f2bf(f0.x); pk[1] = (short)f2bf(f0.y);
        pk[2] = (short)f2bf(f0.z); pk[3] = (short)f2bf(f0.w);
        pk[4] = (short)f2bf(f1.x); pk[5] = (short)f2bf(f1.y);
        pk[6] = (short)f2bf(f1.z); pk[7] = (short)f2bf(f1.w);
        *(short8*)&As[(m * 17 + u) * 8] = pk;
      }
    }
    __syncthreads();

    if (j != rprev) {
      const unsigned short* wr = wT + j * 16384;
      #pragma unroll
      for (int ns = 0; ns < 2; ++ns)
        #pragma unroll
        for (int kk = 0; kk < 4; ++kk)
          bfr[ns][kk] = *(const short8*)(wr + (wave * 32 + ns * 16 + l15) * 128 + kk * 32 + q * 8);
      rprev = j;
    }

    f32x4 acc[4][2];
    #pragma unroll
    for (int ms = 0; ms < 4; ++ms)
      #pragma unroll
      for (int ns = 0; ns < 2; ++ns)
        acc[ms][ns] = (f32x4){0.f, 0.f, 0.f, 0.f};
    #pragma unroll
    for (int kk = 0; kk < 4; ++kk) {
      short8 af[4];
      #pragma unroll
      for (int ms = 0; ms < 4; ++ms)
        af[ms] = *(const short8*)&As[((ms * 16 + l15) * 17 + kk * 4 + q) * 8];
      #pragma unroll
      for (int ms = 0; ms < 4; ++ms)
        #pragma unroll
        for (int ns = 0; ns < 2; ++ns)
          acc[ms][ns] = __builtin_amdgcn_mfma_f32_16x16x32_bf16(af[ms], bfr[ns][kk], acc[ms][ns], 0, 0, 0);
    }

    if (msgmode) {
      __syncthreads();
      #pragma unroll
      for (int ms = 0; ms < 4; ++ms)
        #pragma unroll
        for (int ns = 0; ns < 2; ++ns)
          #pragma unroll
          for (int reg = 0; reg < 4; ++reg)
            Es[(ms * 16 + q * 4 + reg) * 136 + wave * 32 + ns * 16 + l15] =
                (short)f2bf(acc[ms][ns][reg]);
      __syncthreads();
      #pragma unroll
      for (int i = 0; i < 4; ++i) {
        int row = wave * 16 + i * 4 + q;
        short8 v = *(const short8*)&Es[row * 136 + l15 * 8];
        if (row < nrows)
          __builtin_nontemporal_store(v,
              (short8*)(msg + (size_t)Pos2[0][row] * 128 + l15 * 8));
      }
      __syncthreads();
    } else {
      #pragma unroll
      for (int ms = 0; ms < 4; ++ms)
        #pragma unroll
        for (int reg = 0; reg < 4; ++reg) {
          int mrow = ms * 16 + q * 4 + reg;
          if (mrow < nrows) {
            float* op = out + (size_t)Rows[mrow] * 128 + wave * 32 + l15;
            unsafeAtomicAdd(op, acc[ms][0][reg]);
            unsafeAtomicAdd(op + 16, acc[ms][1][reg]);
          }
        }
      __syncthreads();
    }
  }
}

// one 16-lane group per dst (4 dsts/wave): dwordx4 row loads, fp32 accumulate, one store
__global__ __launch_bounds__(256) void k_reduce(const unsigned short* __restrict__ msg,
    const int* __restrict__ dstOff, float* __restrict__ out)
{
  int d = blockIdx.x * 16 + (threadIdx.x >> 4);
  if (d >= NN) return;
  int sl = threadIdx.x & 15;
  int s = dstOff[d], e = dstOff[d + 1];
  const unsigned short* base = msg + (size_t)sl * 8;
  float a[8], bacc[8];
  #pragma unroll
  for (int i = 0; i < 8; ++i) { a[i] = 0.f; bacc[i] = 0.f; }
  int j = s;
  for (; j + 1 < e; j += 2) {
    u32x4 v0 = __builtin_nontemporal_load((const u32x4*)(base + (size_t)j * 128));
    u32x4 v1 = __builtin_nontemporal_load((const u32x4*)(base + (size_t)(j + 1) * 128));
    #pragma unroll
    for (int c = 0; c < 4; ++c) {
      a[2 * c]     += __builtin_bit_cast(float, v0[c] << 16);
      a[2 * c + 1] += __builtin_bit_cast(float, v0[c] & 0xffff0000u);
      bacc[2 * c]     += __builtin_bit_cast(float, v1[c] << 16);
      bacc[2 * c + 1] += __builtin_bit_cast(float, v1[c] & 0xffff0000u);
    }
  }
  if (j < e) {
    u32x4 v0 = __builtin_nontemporal_load((const u32x4*)(base + (size_t)j * 128));
    #pragma unroll
    for (int c = 0; c < 4; ++c) {
      a[2 * c]     += __builtin_bit_cast(float, v0[c] << 16);
      a[2 * c + 1] += __builtin_bit_cast(float, v0[c] & 0xffff0000u);
    }
  }
  f32x4 w0, w1;
  w0[0] = a[0] + bacc[0]; w0[1] = a[1] + bacc[1]; w0[2] = a[2] + bacc[2]; w0[3] = a[3] + bacc[3];
  w1[0] = a[4] + bacc[4]; w1[1] = a[5] + bacc[5]; w1[2] = a[6] + bacc[6]; w1[3] = a[7] + bacc[7];
  float* op = out + (size_t)d * 128 + sl * 8;
  __builtin_nontemporal_store(w0, (f32x4*)op);
  __builtin_nontemporal_store(w1, (f32x4*)(op + 4));
}

extern "C" void kernel_launch(void* const* d_in, const int* in_sizes, int n_in,
                              void* d_out, int out_size, void* d_ws, size_t ws_size,
                              hipStream_t stream)
{
  const float* x      = (const float*)d_in[0];
  const int*   ei     = (const int*)d_in[1];
  const int*   et     = (const int*)d_in[2];
  const float* bases  = (const float*)d_in[3];
  const float* coef   = (const float*)d_in[4];
  const float* w_self = (const float*)d_in[5];
  float* out = (float*)d_out;
  char* ws = (char*)d_ws;
  unsigned short* wT = (unsigned short*)(ws + WT_OFF);
  int* meta      = (int*)(ws + META_OFF);
  int* dstHist   = (int*)(ws + DH_OFF);
  int* dstOff    = (int*)(ws + DO_OFF);
  int* dstCursor = (int*)(ws + DC_OFF);
  int* blockSums = (int*)(ws + BS_OFF);
  int2* sCP      = (int2*)(ws + SCP_OFF);
  int* sRow      = (int*)(ws + SR_OFF);
  unsigned short* xb = (unsigned short*)(ws + XB_OFF);

  const int modeB = (ws_size >= NEED_B) ? 1 : 0;
  const int modeA = (modeB || ws_size >= NEED_A) ? 1 : 0;
  unsigned short* msg = (unsigned short*)(ws + (modeB ? MSGB_OFF : MSGA_OFF));

  hipMemsetAsync(ws + META_OFF, 0, 2560 + 400000, stream);  // meta + dstHist
  k_prep<<<modeB ? (WGRID + 12500) : WGRID, 256, 0, stream>>>(bases, coef, w_self, wT, x, xb);
  k_hist<<<256, 256, 0, stream>>>(ei, et, meta, dstHist);
  if (modeA) {
    k_scan1<<<SCANB, 256, 0, stream>>>(dstHist, dstOff, blockSums);
    k_scan2<<<1, 512, 0, stream>>>(blockSums, meta);
    k_scan3<<<SCANB, 256, 0, stream>>>(dstOff, blockSums, dstCursor, sCP, meta);
  } else {
    k_scan2<<<1, 512, 0, stream>>>(blockSums, meta);
    k_self0<<<SCANB, 256, 0, stream>>>(sCP, sRow, meta);
    hipMemsetAsync(d_out, 0, (size_t)NN * D * 4, stream);
  }
  k_scatter<<<(NE + 4095) / 4096, 256, 0, stream>>>(ei, et, meta, sCP, sRow, dstCursor, modeA);
  k_gemm<<<GEMMG, 256, 0, stream>>>(x, xb, wT, meta, sCP, sRow, msg, out, modeB, modeA);
  if (modeA)
    k_reduce<<<(NN + 15) / 16, 256, 0, stream>>>(msg, dstOff, out);
}